// Round 10
// baseline (188.056 us; speedup 1.0000x reference)
//
#include <hip/hip_runtime.h>
#include <hip/hip_bf16.h>

#define DIM   128
#define NH    8
#define INNER 512
#define HD    64
#define BSZ   4
#define NSEQ  1024
#define PEC   32
#define BH    32   // BSZ*NH

typedef __attribute__((ext_vector_type(4))) float f32x4;
typedef __attribute__((ext_vector_type(2))) float f32x2;
typedef __attribute__((ext_vector_type(8))) short s16x8;
typedef __attribute__((ext_vector_type(4))) unsigned short u16x4;
typedef __attribute__((ext_vector_type(2))) unsigned int u32x2;

__device__ __forceinline__ unsigned short f2bf(float f) {
    unsigned u = __float_as_uint(f);
    u += 0x7fffu + ((u >> 16) & 1u);
    return (unsigned short)(u >> 16);
}

__device__ __forceinline__ float bf2f(short s) {
    return __uint_as_float(((unsigned)(unsigned short)s) << 16);
}

__device__ __forceinline__ s16x8 load8bf(const float* p) {
    f32x4 a = *(const f32x4*)p;
    f32x4 b = *(const f32x4*)(p + 4);
    s16x8 r;
    r[0] = (short)f2bf(a[0]); r[1] = (short)f2bf(a[1]);
    r[2] = (short)f2bf(a[2]); r[3] = (short)f2bf(a[3]);
    r[4] = (short)f2bf(b[0]); r[5] = (short)f2bf(b[1]);
    r[6] = (short)f2bf(b[2]); r[7] = (short)f2bf(b[3]);
    return r;
}

__device__ __forceinline__ f32x4 mfma16(s16x8 a, s16x8 b, f32x4 c) {
    return __builtin_amdgcn_mfma_f32_16x16x32_bf16(a, b, c, 0, 0, 0);
}

// ---------------------------------------------------------------------------
// K1: q/k/v projections.  q_ws,k_ws: bf16 [bh][n][d]  (q pre-scaled by 1/8)
//     vT_ws: bf16 [bh][d][n]  (transposed, bias added)
// ---------------------------------------------------------------------------
__global__ __launch_bounds__(256) void k_qkv(
    const float* __restrict__ x,
    const float* __restrict__ Wq, const float* __restrict__ Wk,
    const float* __restrict__ Wv, const float* __restrict__ bv,
    unsigned short* __restrict__ qws, unsigned short* __restrict__ kws,
    unsigned short* __restrict__ vtws)
{
    int lane = threadIdx.x & 63, wave = threadIdx.x >> 6;
    int lr = lane & 15, lg = lane >> 4;
    int ct   = blockIdx.x * 4 + wave;   // 0..95 column tile over 1536 cols
    int col0 = ct * 16;
    int m0   = blockIdx.y * 16;

    s16x8 a[4];
    const float* xrow = x + (m0 + lr) * DIM;
    #pragma unroll
    for (int kt = 0; kt < 4; ++kt) a[kt] = load8bf(xrow + kt * 32 + lg * 8);

    const float* W; int cbase; int which = col0 >> 9;
    if (which == 0)      { W = Wq; cbase = col0; }
    else if (which == 1) { W = Wk; cbase = col0 - 512; }
    else                 { W = Wv; cbase = col0 - 1024; }

    const float* wrow = W + (cbase + lr) * DIM;
    s16x8 bfr[4];
    #pragma unroll
    for (int kt = 0; kt < 4; ++kt) bfr[kt] = load8bf(wrow + kt * 32 + lg * 8);
    f32x4 acc = {0.f, 0.f, 0.f, 0.f};
    #pragma unroll
    for (int kt = 0; kt < 4; ++kt) acc = mfma16(a[kt], bfr[kt], acc);

    int colW = cbase + lr;          // 0..511 inside this projection
    int h = colW >> 6, d = colW & 63;
    int mB = m0 + lg * 4;           // 4 consecutive rows, same batch
    int b  = mB >> 10;
    int bh = b * NH + h;
    if (which == 2) {
        float bias = bv[colW];
        u16x4 pk;
        #pragma unroll
        for (int v = 0; v < 4; ++v) pk[v] = f2bf(acc[v] + bias);
        int n0 = mB & 1023;
        *(u16x4*)(vtws + (bh * HD + d) * NSEQ + n0) = pk;
    } else {
        #pragma unroll
        for (int v = 0; v < 4; ++v) {
            int n = (mB + v) & 1023;
            float val = acc[v];
            if (which == 0) qws[(bh * NSEQ + n) * HD + d] = f2bf(val * 0.125f);
            else            kws[(bh * NSEQ + n) * HD + d] = f2bf(val);
        }
    }
}

// ---------------------------------------------------------------------------
// K2 v7: k_fattn — fused flash attention, QBLK=16 for occupancy.
//   Per (bh, 16-row i-tile): wave w owns j-quarter; S = mfma(K, q) in 64
//   VGPRs (swapped operands -> per-i stats lane-local).  Cross-wave softmax
//   via 0.5 KB LDS exchange.  P -> 32 KB swizzled LDS; copy-out before PV.
//   32.5 KB LDS + VGPR<=128 -> 4 blocks/CU = 16 waves/CU (2x the QBLK=32 ver).
// grid 2048 (XCD-pinned bh), block 256.
// ---------------------------------------------------------------------------
__global__ __launch_bounds__(256, 4) void k_fattn(
    const unsigned short* __restrict__ qws, const unsigned short* __restrict__ kws,
    const unsigned short* __restrict__ vtws,
    unsigned short* __restrict__ attnw, float* __restrict__ outv)
{
    __shared__ unsigned short Pl[16 * 1024];   // 32 KB P [i-local][j] swizzled
    __shared__ float mlb[4][16][2];            // [wave][lr][{max,sum}]
    int lane = threadIdx.x & 63, wave = threadIdx.x >> 6;
    int lr = lane & 15, lg = lane >> 4;
    int L = blockIdx.x;
    int bh = (L & 7) * 4 + ((L >> 3) & 3);   // XCD-pinned: K/V L2-resident
    int i0 = (L >> 5) * 16;

    auto paddr = [&](int r, int jb) -> char* {
        unsigned mask = (unsigned)(((r & 7) << 4) | ((r & 3) << 7));
        return (char*)Pl + (unsigned)(r * 2048) + ((unsigned)jb ^ mask);
    };

    // q fragments (B operand: B-row = i)
    s16x8 qf0, qf1;
    {
        const unsigned short* qrow = qws + (bh * NSEQ + i0 + lr) * HD;
        qf0 = *(const s16x8*)(qrow + lg * 8);
        qf1 = *(const s16x8*)(qrow + 32 + lg * 8);
    }

    // ---- phase A: S for this wave's j-quarter, in registers ----
    // s[jc][v] = S[j = wave*256+jc*16+lg*4+v][i = i0+lr]
    f32x4 s[16];
    #pragma unroll
    for (int jc = 0; jc < 16; ++jc) {
        const unsigned short* krow =
            kws + (bh * NSEQ + wave * 256 + jc * 16 + lr) * HD + lg * 8;
        s16x8 kf0 = *(const s16x8*)(krow);
        s16x8 kf1 = *(const s16x8*)(krow + 32);
        f32x4 acc = {0.f, 0.f, 0.f, 0.f};
        acc = mfma16(kf0, qf0, acc);
        s[jc] = mfma16(kf1, qf1, acc);
    }

    // wave-local stats per i (lanes sharing lr differ in lg = j groups)
    float mx = -3.0e38f;
    #pragma unroll
    for (int jc = 0; jc < 16; ++jc) {
        f32x4 t = s[jc];
        mx = fmaxf(mx, fmaxf(fmaxf(t[0], t[1]), fmaxf(t[2], t[3])));
    }
    mx = fmaxf(mx, __shfl_xor(mx, 16));
    mx = fmaxf(mx, __shfl_xor(mx, 32));
    float sum = 0.f;
    #pragma unroll
    for (int jc = 0; jc < 16; ++jc) {
        f32x4 t = s[jc];
        #pragma unroll
        for (int u = 0; u < 4; ++u) { t[u] = __expf(t[u] - mx); sum += t[u]; }
        s[jc] = t;
    }
    sum += __shfl_xor(sum, 16);
    sum += __shfl_xor(sum, 32);
    if (lg == 0) {
        mlb[wave][lr][0] = mx;
        mlb[wave][lr][1] = sum;
    }
    __syncthreads();

    // global M, L across the 4 waves; per-wave normalization factor
    float fsc;
    {
        float M = -3.0e38f;
        #pragma unroll
        for (int w = 0; w < 4; ++w) M = fmaxf(M, mlb[w][lr][0]);
        float Ls = 0.f;
        #pragma unroll
        for (int w = 0; w < 4; ++w)
            Ls += mlb[w][lr][1] * __expf(mlb[w][lr][0] - M);
        fsc = __expf(mx - M) / Ls;
    }

    // scale + pack bf16 -> LDS P (wave-private j columns, disjoint)
    #pragma unroll
    for (int jc = 0; jc < 16; ++jc) {
        f32x4 t = s[jc];
        unsigned lo = (unsigned)f2bf(t[0] * fsc) | ((unsigned)f2bf(t[1] * fsc) << 16);
        unsigned hi = (unsigned)f2bf(t[2] * fsc) | ((unsigned)f2bf(t[3] * fsc) << 16);
        u32x2 pk = {lo, hi};
        int jb = (wave * 512) + (jc * 32) + (lg * 8);   // byte offset = j*2
        *(u32x2*)paddr(lr, jb) = pk;
    }
    __syncthreads();

    // ---- P copy-out FIRST: stores drain under the PV MFMAs below ----
    #pragma unroll
    for (int r4 = 0; r4 < 4; ++r4) {
        int r = wave * 4 + r4;
        unsigned short* grow = attnw + ((size_t)(i0 + r) * BH + bh) * NSEQ;
        #pragma unroll
        for (int half = 0; half < 2; ++half) {
            int j = half * 512 + lane * 8;
            s16x8 val = *(s16x8*)paddr(r, j * 2);
            *(s16x8*)(grow + j) = val;
        }
    }

    // ---- phase B: PV; wave owns d-16 (all j from LDS) ----
    int d0 = wave * 16;
    const unsigned short* vrow = vtws + (bh * HD + d0 + lr) * NSEQ + lg * 8;
    f32x4 o0 = {0.f, 0.f, 0.f, 0.f};
    #pragma unroll
    for (int kt = 0; kt < 32; ++kt) {
        s16x8 bf = *(const s16x8*)(vrow + kt * 32);
        s16x8 a0 = *(s16x8*)paddr(lr, kt * 64 + lg * 16);
        o0 = mfma16(a0, bf, o0);
    }
    float* orow = outv + (bh * NSEQ + i0) * HD;
    #pragma unroll
    for (int v = 0; v < 4; ++v)
        orow[(lg * 4 + v) * HD + d0 + lr] = o0[v];
}

// ---------------------------------------------------------------------------
// K3 v5: k_pe — 8-wave blocks, wave-private j-eighths, aliased LDS.
//   pes[bh][i][c] = attn[i] (32bh x 1024j) @ pe[i] (1024j x 32c).
//   Wave w owns j in [w*128,(w+1)*128): 4 MFMA-steps (half the chain of v3);
//   pe staged issue/commit through a PRIVATE dbuf LDS region (no barriers in
//   loop); A-frags loaded per-step from global (TLP hides).  The partial-sum
//   buffer ALIASES the same per-wave 5 KB region (own-wave writes only; all
//   cross-wave reads after the single barrier).  LDS exactly 40 KB ->
//   4 blocks/CU = 32 waves/CU.
// grid 1024, block 512.
// ---------------------------------------------------------------------------
__global__ __launch_bounds__(512) void k_pe(
    const unsigned short* __restrict__ attnw, const float* __restrict__ pe,
    float* __restrict__ pes)
{
    __shared__ char smem[8][5120];   // per-wave: pt [2][32][40]x2B, then part [32][32]f32
    int i = blockIdx.x;
    int lane = threadIdx.x & 63, wave = threadIdx.x >> 6;   // 8 waves
    int lr = lane & 15, lg = lane >> 4;
    int jp = lane & 15, cg = lane >> 4;            // staging roles
    const float* pei = pe + (size_t)i * NSEQ * PEC;
    int jbase = wave * 128;

    typedef unsigned short pt_t[PEC][40];
    pt_t* pt = (pt_t*)smem[wave];                  // pt[2][32][40]

    f32x4 r0, r1, r2, r3;        // pe stage registers (2 j x 8 c per lane)
    auto issue = [&](int t) {
        const float* s0 = pei + (size_t)(jbase + t * 32 + jp * 2) * PEC + cg * 8;
        r0 = *(const f32x4*)(s0);
        r1 = *(const f32x4*)(s0 + 4);
        r2 = *(const f32x4*)(s0 + PEC);
        r3 = *(const f32x4*)(s0 + PEC + 4);
    };
    auto commit = [&](int buf) {   // pack bf16 pairs -> pt[buf][c][j0..1]
        #pragma unroll
        for (int cc = 0; cc < 4; ++cc) {
            unsigned lo = f2bf(r0[cc]), hi = f2bf(r2[cc]);
            *(unsigned*)&pt[buf][cg * 8 + cc][jp * 2] = lo | (hi << 16);
        }
        #pragma unroll
        for (int cc = 0; cc < 4; ++cc) {
            unsigned lo = f2bf(r1[cc]), hi = f2bf(r3[cc]);
            *(unsigned*)&pt[buf][cg * 8 + 4 + cc][jp * 2] = lo | (hi << 16);
        }
    };

    const unsigned short* a0base =
        attnw + ((size_t)i * BH + lr) * NSEQ + jbase + lg * 8;
    const unsigned short* a1base = a0base + 16 * NSEQ;

    f32x4 acc00 = {0.f,0.f,0.f,0.f}, acc01 = {0.f,0.f,0.f,0.f};
    f32x4 acc10 = {0.f,0.f,0.f,0.f}, acc11 = {0.f,0.f,0.f,0.f};

    issue(0); commit(0);
    issue(1);
    #pragma unroll
    for (int t = 0; t < 4; ++t) {
        int cur = t & 1;
        s16x8 af0 = *(const s16x8*)(a0base + t * 32);
        s16x8 af1 = *(const s16x8*)(a1base + t * 32);
        s16x8 bf0 = *(const s16x8*)&pt[cur][lr][lg * 8];
        s16x8 bf1 = *(const s16x8*)&pt[cur][16 + lr][lg * 8];
        acc00 = mfma16(af0, bf0, acc00);
        acc01 = mfma16(af0, bf1, acc01);
        acc10 = mfma16(af1, bf0, acc10);
        acc11 = mfma16(af1, bf1, acc11);
        if (t < 3) {
            commit(cur ^ 1);         // regs currently hold tile t+1
            if (t < 2) issue(t + 2);
        }
    }

    // partials into OWN region (pt fully consumed by this wave already)
    float (*part)[PEC] = (float (*)[PEC])smem[wave];   // [32][32]
    #pragma unroll
    for (int v = 0; v < 4; ++v) {
        part[lg * 4 + v][lr]           = acc00[v];
        part[lg * 4 + v][16 + lr]      = acc01[v];
        part[16 + lg * 4 + v][lr]      = acc10[v];
        part[16 + lg * 4 + v][16 + lr] = acc11[v];
    }
    __syncthreads();

    // reduce 8 wave-partials: 512 threads x 2 outputs
    int tid = threadIdx.x;
    int bh = tid >> 4, c0 = (tid & 15) * 2;
    float s0 = 0.f, s1 = 0.f;
    #pragma unroll
    for (int w = 0; w < 8; ++w) {
        const float* pw = (const float*)smem[w];
        s0 += pw[bh * PEC + c0];
        s1 += pw[bh * PEC + c0 + 1];
    }
    float* dst = pes + ((size_t)bh * NSEQ + i) * PEC + c0;
    dst[0] = s0;
    dst[1] = s1;
}

// ---------------------------------------------------------------------------
// K4: t[b][n][h*64+d] = outv + pes @ Wpe^T + bpe   (bf16 packed)
// ---------------------------------------------------------------------------
__global__ __launch_bounds__(256) void k_comb(
    const float* __restrict__ outv, const float* __restrict__ pes,
    const float* __restrict__ Wpe, const float* __restrict__ bpe,
    unsigned short* __restrict__ tws)
{
    __shared__ float wpe_s[HD * PEC];
    __shared__ float bpe_s[HD];
    int tid = threadIdx.x;
    for (int idx = tid; idx < HD * PEC; idx += 256) wpe_s[idx] = Wpe[idx];
    if (tid < HD) bpe_s[tid] = bpe[tid];
    __syncthreads();

    int bh = blockIdx.y;
    int n  = blockIdx.x * 32 + (tid >> 3);
    int d0 = (tid & 7) * 8;
    int b = bh >> 3, h = bh & 7;

    float pr[PEC];
    const float* prow = pes + (bh * NSEQ + n) * PEC;
    #pragma unroll
    for (int c = 0; c < PEC; c += 4) {
        f32x4 t = *(const f32x4*)(prow + c);
        pr[c] = t[0]; pr[c + 1] = t[1]; pr[c + 2] = t[2]; pr[c + 3] = t[3];
    }
    const float* ovp = outv + (bh * NSEQ + n) * HD + d0;
    s16x8 pk;
    #pragma unroll
    for (int dd = 0; dd < 8; ++dd) {
        float acc = bpe_s[d0 + dd] + ovp[dd];
        const float* wrow = &wpe_s[(d0 + dd) * PEC];
        #pragma unroll
        for (int c = 0; c < PEC; ++c) acc += pr[c] * wrow[c];
        pk[dd] = (short)f2bf(acc);
    }
    *(s16x8*)(tws + (b * NSEQ + n) * INNER + h * HD + d0) = pk;
}

// ---------------------------------------------------------------------------
// K5: out[b][n][:] = t @ Wproj^T    (4096 x 128, K=512)
// ---------------------------------------------------------------------------
__global__ __launch_bounds__(256) void k_proj(
    const unsigned short* __restrict__ tws, const float* __restrict__ Wproj,
    float* __restrict__ out)
{
    int lane = threadIdx.x & 63, wave = threadIdx.x >> 6;
    int lr = lane & 15, lg = lane >> 4;
    int n0 = (blockIdx.x * 4 + wave) * 16;
    int m0 = blockIdx.y * 16;
    const unsigned short* arow = tws + (m0 + lr) * INNER;
    const float* brow = Wproj + (n0 + lr) * INNER;
    s16x8 afr[16];
    #pragma unroll
    for (int kt = 0; kt < 16; ++kt)
        afr[kt] = *(const s16x8*)(arow + kt * 32 + lg * 8);
    f32x4 acc = {0.f, 0.f, 0.f, 0.f};
    #pragma unroll
    for (int kt = 0; kt < 16; ++kt) {
        s16x8 bfr = load8bf(brow + kt * 32 + lg * 8);
        acc = mfma16(afr[kt], bfr, acc);
    }
    #pragma unroll
    for (int v = 0; v < 4; ++v)
        out[(m0 + lg * 4 + v) * DIM + n0 + lr] = acc[v];
}

// ---------------------------------------------------------------------------
// Workspace layout (92 MiB total):
//   [ 0,  4) MiB q_ws   bf16 [bh][n][64]
//   [ 4,  8) MiB k_ws   bf16 [bh][n][64]
//   [ 8, 12) MiB vT_ws  bf16 [bh][64][n]
//   [12, 76) MiB attn   bf16 [i][bh][j]   (normalized P)
//   [76, 84) MiB outv   f32  [bh][n][64]
//   [84, 88) MiB pes    f32  [bh][n][32]
//   [88, 92) MiB t      bf16 [b][n][512]
// ---------------------------------------------------------------------------
extern "C" void kernel_launch(void* const* d_in, const int* in_sizes, int n_in,
                              void* d_out, int out_size, void* d_ws, size_t ws_size,
                              hipStream_t stream)
{
    const float* x     = (const float*)d_in[0];
    const float* pe    = (const float*)d_in[1];
    const float* Wq    = (const float*)d_in[2];
    const float* Wk    = (const float*)d_in[3];
    const float* Wv    = (const float*)d_in[4];
    const float* bv    = (const float*)d_in[5];
    const float* Wproj = (const float*)d_in[6];
    const float* Wpe   = (const float*)d_in[7];
    const float* bpe   = (const float*)d_in[8];
    float* out = (float*)d_out;

    char* ws = (char*)d_ws;
    unsigned short* qws  = (unsigned short*)(ws);
    unsigned short* kws  = (unsigned short*)(ws + ( 4u << 20));
    unsigned short* vtws = (unsigned short*)(ws + ( 8u << 20));
    unsigned short* attn = (unsigned short*)(ws + (12u << 20));
    float*          outv = (float*)         (ws + (76u << 20));
    float*          pes  = (float*)         (ws + (84u << 20));
    unsigned short* tws  = (unsigned short*)(ws + (88u << 20));

    k_qkv  <<<dim3(24, 256), 256, 0, stream>>>(x, Wq, Wk, Wv, bv, qws, kws, vtws);
    k_fattn<<<dim3(2048),    256, 0, stream>>>(qws, kws, vtws, attn, outv);
    k_pe   <<<dim3(1024),    512, 0, stream>>>(attn, pe, pes);
    k_comb <<<dim3(32, 32),  256, 0, stream>>>(outv, pes, Wpe, bpe, tws);
    k_proj <<<dim3(2, 256),  256, 0, stream>>>(tws, Wproj, out);
}